// Round 10
// baseline (38.983 us; speedup 1.0000x reference)
//
#include <hip/hip_runtime.h>

#define B_ROWS 2048
#define C_TOTAL 1000
#define C_LOADED 256
#define NEG_PEN 0.03f
#define NLINES 64

// ws layout:
//   [0     : 16384) ull pv[2048]  per-row packed {partial_sum, valid_flag}
//   [16384 : 20480) 64 counter lines, 64B apart (uint at line start)
//   [20480 : 20544) level-2 counter (own line)
//
// Mod-window completion detection (scan-free, spin-free, init-insensitive):
// any contiguous run of 32 increments of a uint contains exactly one
// returned old-value == 31 (mod 32), regardless of starting value (fresh 0,
// poison 0xAAAAAAAA, or accumulated across graph replays). That block bumps
// the level-2 counter; the unique old == 63 (mod 64) there finalizes.
// Exactly one finalizer per call; counters never need resetting.

union PVU { unsigned long long u; float2 f; };

__global__ void __launch_bounds__(C_LOADED)
rank_loss_fused(const float* __restrict__ ranks,
                const int* __restrict__ labels,
                const int* __restrict__ ids,
                unsigned long long* __restrict__ pv,
                unsigned int* __restrict__ lines,   // 64 lines x 16 uints
                unsigned int* __restrict__ lvl2,
                float* __restrict__ out) {
    __shared__ __align__(16) float negl[264];   // compacted r_neg + pen, padded
    __shared__ float posl[256];                 // compacted r_pos
    __shared__ float wave_sums[4];
    __shared__ int wb_n[4], wb_p[4];
    __shared__ int ncnt, pcnt, finflag;
    __shared__ float red_s[4], red_v[4];

    const int b = blockIdx.x;
    const int t = threadIdx.x;
    const int lane = t & 63;
    const int wave = t >> 6;

    if (t == 0) { ncnt = 0; pcnt = 0; finflag = 0; }

    // gather: thread t owns gathered column t (duplicate ids = duplicate
    // threads — matches reference semantics; verified absmax=0 in R1-R9)
    const int c = ids[t];
    const float r = ranks[b * C_TOTAL + c];
    const int lab = labels[b * C_TOTAL + c];
    const bool isneg = (lab == 0);

    // wave-level compaction of BOTH lists (order-independent sum)
    const unsigned long long m = __ballot(isneg);
    const unsigned long long lm = (1ULL << lane) - 1ULL;
    const int nneg_w = __popcll(m);
    const int my_n = __popcll(m & lm);
    const int my_p = __popcll(~m & lm);

    __syncthreads();                      // counters zeroed
    if (lane == 0) {
        wb_n[wave] = atomicAdd(&ncnt, nneg_w);
        wb_p[wave] = atomicAdd(&pcnt, 64 - nneg_w);
    }
    __syncthreads();

    const int N = ncnt;                   // negatives in this row
    const int P = C_LOADED - N;           // positives
    const int Npad = (N + 7) & ~7;
    if (isneg) negl[wb_n[wave] + my_n] = r + NEG_PEN;
    else       posl[wb_p[wave] + my_p] = r;
    if (t >= N && t < Npad) negl[t] = -1e30f;   // pad -> relu==0
    __syncthreads();

    float acc = 0.f;
    if (t < P) {                          // positives packed low: idle waves skip
        const float rp = posl[t];
        float a0 = 0.f, a1 = 0.f, a2 = 0.f, a3 = 0.f;
        float a4 = 0.f, a5 = 0.f, a6 = 0.f, a7 = 0.f;
        const float4* n4 = (const float4*)negl;
        const int G = Npad >> 2;
        for (int g = 0; g < G; g += 2) {
            float4 x = n4[g];             // LDS broadcast reads
            float4 y = n4[g + 1];
            a0 += fmaxf(x.x - rp, 0.0f);
            a1 += fmaxf(x.y - rp, 0.0f);
            a2 += fmaxf(x.z - rp, 0.0f);
            a3 += fmaxf(x.w - rp, 0.0f);
            a4 += fmaxf(y.x - rp, 0.0f);
            a5 += fmaxf(y.y - rp, 0.0f);
            a6 += fmaxf(y.z - rp, 0.0f);
            a7 += fmaxf(y.w - rp, 0.0f);
        }
        acc = ((a0 + a1) + (a2 + a3)) + ((a4 + a5) + (a6 + a7));
    }

    // wave reduction
#pragma unroll
    for (int off = 32; off > 0; off >>= 1) {
        acc += __shfl_down(acc, off, 64);
    }
    if (lane == 0) wave_sums[wave] = acc;
    __syncthreads();

    if (t == 0) {
        PVU v;
        v.f = make_float2(
            (wave_sums[0] + wave_sums[1]) + (wave_sums[2] + wave_sums[3]),
            (P > 0) ? 1.0f : 0.0f);
        __hip_atomic_store(&pv[b], v.u, __ATOMIC_RELAXED,
                           __HIP_MEMORY_SCOPE_AGENT);
        // one returned add to my line (release orders pv store before it)
        unsigned int v1 = __hip_atomic_fetch_add(&lines[(b & (NLINES - 1)) * 16],
                                                 1u, __ATOMIC_ACQ_REL,
                                                 __HIP_MEMORY_SCOPE_AGENT);
        if ((v1 & 31u) == 31u) {          // unique line-closer this call
            unsigned int v2 = __hip_atomic_fetch_add(lvl2, 1u, __ATOMIC_ACQ_REL,
                                                     __HIP_MEMORY_SCOPE_AGENT);
            if ((v2 & 63u) == 63u) finflag = 1;   // unique last block
        }
    }
    __syncthreads();

    if (finflag) {                        // exactly one block per call
        float ssum = 0.f, svld = 0.f;
#pragma unroll
        for (int k = 0; k < 8; ++k) {
            PVU v;
            v.u = __hip_atomic_load(&pv[t * 8 + k], __ATOMIC_RELAXED,
                                    __HIP_MEMORY_SCOPE_AGENT);
            ssum += v.f.x;
            svld += v.f.y;
        }
#pragma unroll
        for (int off = 32; off > 0; off >>= 1) {
            ssum += __shfl_down(ssum, off, 64);
            svld += __shfl_down(svld, off, 64);
        }
        if (lane == 0) { red_s[wave] = ssum; red_v[wave] = svld; }
        __syncthreads();
        if (t == 0) {
            float ts = (red_s[0] + red_s[1]) + (red_s[2] + red_s[3]);
            float tv = (red_v[0] + red_v[1]) + (red_v[2] + red_v[3]);
            out[0] = ts / tv;
        }
    }
}

extern "C" void kernel_launch(void* const* d_in, const int* in_sizes, int n_in,
                              void* d_out, int out_size, void* d_ws, size_t ws_size,
                              hipStream_t stream) {
    const float* ranks  = (const float*)d_in[0];
    const int*   labels = (const int*)d_in[1];
    const int*   ids    = (const int*)d_in[2];
    float* out = (float*)d_out;

    unsigned long long* pv = (unsigned long long*)d_ws;
    unsigned int* lines = (unsigned int*)((char*)d_ws + 16384);
    unsigned int* lvl2  = (unsigned int*)((char*)d_ws + 20480);

    rank_loss_fused<<<B_ROWS, C_LOADED, 0, stream>>>(ranks, labels, ids,
                                                     pv, lines, lvl2, out);
}

// Round 11
// 12.116 us; speedup vs baseline: 3.2175x; 3.2175x over previous
//
#include <hip/hip_runtime.h>

#define B_ROWS 2048
#define C_TOTAL 1000
#define C_LOADED 256
#define NEG_PEN 0.03f
#define NLINES 64

// ws layout:
//   [0     : 16384) ull pv[2048]  per-row packed {partial_sum, valid_flag}
//   [16384 : 20480) 64 counter lines, 64B apart (uint at line start)
//   [20480 : 20544) level-2 counter (own line)
//
// Mod-window completion detection (scan-free, spin-free, init-insensitive):
// any contiguous run of 32 increments of a uint contains exactly one
// returned old-value == 31 (mod 32), regardless of starting value. That
// block bumps lvl2; the unique old == 63 (mod 64) there finalizes. Exactly
// one finalizer per call; counters never reset (graph-replay safe).
//
// Memory ordering WITHOUT acquire/release (gfx9xx agent-scope acq/rel emit
// whole-L2 writeback/invalidate ops — 2048 of them cost ~35 us, the R6/R7/
// R10 failure): all atomics RELAXED (execute at coherence point, bypass
// local caches). pv published via returned atomic exchange; explicit
// s_waitcnt vmcnt(0) orders its completion before the line bump; returned-
// value data deps order line->lvl2->finalize; finalizer reads pv with
// relaxed agent atomic loads. LLC (point of coherence) orders everything.

union PVU { unsigned long long u; float2 f; };

__global__ void __launch_bounds__(C_LOADED)
rank_loss_fused(const float* __restrict__ ranks,
                const int* __restrict__ labels,
                const int* __restrict__ ids,
                unsigned long long* __restrict__ pv,
                unsigned int* __restrict__ lines,   // 64 lines x 16 uints
                unsigned int* __restrict__ lvl2,
                float* __restrict__ out) {
    __shared__ __align__(16) float negl[264];   // compacted r_neg + pen, padded
    __shared__ float posl[256];                 // compacted r_pos
    __shared__ float wave_sums[4];
    __shared__ int wb_n[4], wb_p[4];
    __shared__ int ncnt, pcnt, finflag;
    __shared__ float red_s[4], red_v[4];

    const int b = blockIdx.x;
    const int t = threadIdx.x;
    const int lane = t & 63;
    const int wave = t >> 6;

    if (t == 0) { ncnt = 0; pcnt = 0; finflag = 0; }

    // gather: thread t owns gathered column t (duplicate ids = duplicate
    // threads — matches reference semantics; verified absmax=0 in R1-R10)
    const int c = ids[t];
    const float r = ranks[b * C_TOTAL + c];
    const int lab = labels[b * C_TOTAL + c];
    const bool isneg = (lab == 0);

    // wave-level compaction of BOTH lists (order-independent sum)
    const unsigned long long m = __ballot(isneg);
    const unsigned long long lm = (1ULL << lane) - 1ULL;
    const int nneg_w = __popcll(m);
    const int my_n = __popcll(m & lm);
    const int my_p = __popcll(~m & lm);

    __syncthreads();                      // counters zeroed
    if (lane == 0) {
        wb_n[wave] = atomicAdd(&ncnt, nneg_w);
        wb_p[wave] = atomicAdd(&pcnt, 64 - nneg_w);
    }
    __syncthreads();

    const int N = ncnt;                   // negatives in this row
    const int P = C_LOADED - N;           // positives
    const int Npad = (N + 7) & ~7;
    if (isneg) negl[wb_n[wave] + my_n] = r + NEG_PEN;
    else       posl[wb_p[wave] + my_p] = r;
    if (t >= N && t < Npad) negl[t] = -1e30f;   // pad -> relu==0
    __syncthreads();

    float acc = 0.f;
    if (t < P) {                          // positives packed low: idle waves skip
        const float rp = posl[t];
        float a0 = 0.f, a1 = 0.f, a2 = 0.f, a3 = 0.f;
        float a4 = 0.f, a5 = 0.f, a6 = 0.f, a7 = 0.f;
        const float4* n4 = (const float4*)negl;
        const int G = Npad >> 2;
        for (int g = 0; g < G; g += 2) {
            float4 x = n4[g];             // LDS broadcast reads
            float4 y = n4[g + 1];
            a0 += fmaxf(x.x - rp, 0.0f);
            a1 += fmaxf(x.y - rp, 0.0f);
            a2 += fmaxf(x.z - rp, 0.0f);
            a3 += fmaxf(x.w - rp, 0.0f);
            a4 += fmaxf(y.x - rp, 0.0f);
            a5 += fmaxf(y.y - rp, 0.0f);
            a6 += fmaxf(y.z - rp, 0.0f);
            a7 += fmaxf(y.w - rp, 0.0f);
        }
        acc = ((a0 + a1) + (a2 + a3)) + ((a4 + a5) + (a6 + a7));
    }

    // wave reduction
#pragma unroll
    for (int off = 32; off > 0; off >>= 1) {
        acc += __shfl_down(acc, off, 64);
    }
    if (lane == 0) wave_sums[wave] = acc;
    __syncthreads();

    if (t == 0) {
        PVU v;
        v.f = make_float2(
            (wave_sums[0] + wave_sums[1]) + (wave_sums[2] + wave_sums[3]),
            (P > 0) ? 1.0f : 0.0f);
        // publish via RMW (executes at coherence point, no cache residue)
        (void)__hip_atomic_exchange(&pv[b], v.u, __ATOMIC_RELAXED,
                                    __HIP_MEMORY_SCOPE_AGENT);
        // order: pv exchange completed at LLC before the line bump issues
        asm volatile("s_waitcnt vmcnt(0)" ::: "memory");
        unsigned int v1 = __hip_atomic_fetch_add(&lines[(b & (NLINES - 1)) * 16],
                                                 1u, __ATOMIC_RELAXED,
                                                 __HIP_MEMORY_SCOPE_AGENT);
        if ((v1 & 31u) == 31u) {          // unique line-closer this call
            // v1 return-value dep: line add already completed at LLC
            unsigned int v2 = __hip_atomic_fetch_add(lvl2, 1u, __ATOMIC_RELAXED,
                                                     __HIP_MEMORY_SCOPE_AGENT);
            if ((v2 & 63u) == 63u) finflag = 1;   // unique last block
        }
    }
    __syncthreads();

    if (finflag) {                        // exactly one block per call
        float ssum = 0.f, svld = 0.f;
#pragma unroll
        for (int k = 0; k < 8; ++k) {
            PVU v;
            v.u = __hip_atomic_load(&pv[t * 8 + k], __ATOMIC_RELAXED,
                                    __HIP_MEMORY_SCOPE_AGENT);
            ssum += v.f.x;
            svld += v.f.y;
        }
#pragma unroll
        for (int off = 32; off > 0; off >>= 1) {
            ssum += __shfl_down(ssum, off, 64);
            svld += __shfl_down(svld, off, 64);
        }
        if (lane == 0) { red_s[wave] = ssum; red_v[wave] = svld; }
        __syncthreads();
        if (t == 0) {
            float ts = (red_s[0] + red_s[1]) + (red_s[2] + red_s[3]);
            float tv = (red_v[0] + red_v[1]) + (red_v[2] + red_v[3]);
            out[0] = ts / tv;
        }
    }
}

extern "C" void kernel_launch(void* const* d_in, const int* in_sizes, int n_in,
                              void* d_out, int out_size, void* d_ws, size_t ws_size,
                              hipStream_t stream) {
    const float* ranks  = (const float*)d_in[0];
    const int*   labels = (const int*)d_in[1];
    const int*   ids    = (const int*)d_in[2];
    float* out = (float*)d_out;

    unsigned long long* pv = (unsigned long long*)d_ws;
    unsigned int* lines = (unsigned int*)((char*)d_ws + 16384);
    unsigned int* lvl2  = (unsigned int*)((char*)d_ws + 20480);

    rank_loss_fused<<<B_ROWS, C_LOADED, 0, stream>>>(ranks, labels, ids,
                                                     pv, lines, lvl2, out);
}

// Round 12
// 11.953 us; speedup vs baseline: 3.2612x; 1.0136x over previous
//
#include <hip/hip_runtime.h>

#define B_ROWS 2048
#define C_TOTAL 1000
#define C_LOADED 256
#define NEG_PEN 0.03f
#define NLINES 64
#define WPB 4                    // waves (=rows) per block
#define GRID (B_ROWS / WPB)      // 512

// ws layout:
//   [0     : 16384) ull pv[2048]  per-row packed {partial_sum, valid_flag}
//   [16384 : 20480) 64 counter lines, 64B apart (uint at line start)
//   [20480 : 20544) level-2 counter (own line)
//
// Mod-window completion detection (R9/R11, proven): any contiguous run of 32
// increments returns exactly one old == 31 (mod 32) regardless of initial
// value; that row's wave bumps lvl2; unique old == 63 (mod 64) finalizes.
// All atomics RELAXED agent-scope (no acq/rel -> no L2 wb/inv storms, the
// R6/R7/R10 failure); ordering via returned-RMW-at-LLC + s_waitcnt vmcnt(0).
//
// This version: ONE WAVE PER ROW, zero __syncthreads. Compaction via 4
// ballots + prefix bases; wave-synchronous LDS (lgkmcnt(0)); finalize done
// by a single wave.

union PVU { unsigned long long u; float2 f; };

template<int QMAX>
__device__ __forceinline__ float pair_loop(const float4* __restrict__ n4, int G,
                                           float rp0, float rp1,
                                           float rp2, float rp3) {
    float a0 = 0.f, a1 = 0.f, a2 = 0.f, a3 = 0.f;
    for (int g = 0; g < G; g += 2) {
        float4 x = n4[g];                 // broadcast LDS reads
        float4 y = n4[g + 1];
        float v[8] = {x.x, x.y, x.z, x.w, y.x, y.y, y.z, y.w};
#pragma unroll
        for (int e = 0; e < 8; ++e) {
            a0 += fmaxf(v[e] - rp0, 0.f);
            if (QMAX > 1) a1 += fmaxf(v[e] - rp1, 0.f);
            if (QMAX > 2) a2 += fmaxf(v[e] - rp2, 0.f);
            if (QMAX > 3) a3 += fmaxf(v[e] - rp3, 0.f);
        }
    }
    return (a0 + a1) + (a2 + a3);
}

__global__ void __launch_bounds__(256)
rank_loss_fused(const float* __restrict__ ranks,
                const int* __restrict__ labels,
                const int* __restrict__ ids,
                unsigned long long* __restrict__ pv,
                unsigned int* __restrict__ lines,   // 64 lines x 16 uints
                unsigned int* __restrict__ lvl2,
                float* __restrict__ out) {
    __shared__ __align__(16) float negl[WPB][264];  // per-wave compacted negs
    __shared__ __align__(16) float posl[WPB][256];  // per-wave compacted pos

    const int t = threadIdx.x;
    const int lane = t & 63;
    const int wave = t >> 6;
    const int row = blockIdx.x * WPB + wave;

    // ids is 1KB, L1-hot; each lane owns columns lane+64k (sorted ids ->
    // adjacent lanes hit adjacent addresses in the gathers below)
    const int c0 = ids[lane];
    const int c1 = ids[lane + 64];
    const int c2 = ids[lane + 128];
    const int c3 = ids[lane + 192];
    const int base = row * C_TOTAL;
    const float r0 = ranks[base + c0], r1 = ranks[base + c1];
    const float r2 = ranks[base + c2], r3 = ranks[base + c3];
    const int l0 = labels[base + c0], l1 = labels[base + c1];
    const int l2 = labels[base + c2], l3 = labels[base + c3];

    // wave-synchronous compaction: 4 ballots + prefix bases, no atomics
    const unsigned long long m0 = __ballot(l0 == 0);
    const unsigned long long m1 = __ballot(l1 == 0);
    const unsigned long long m2 = __ballot(l2 == 0);
    const unsigned long long m3 = __ballot(l3 == 0);
    const int n0 = __popcll(m0), n1 = __popcll(m1);
    const int n2 = __popcll(m2), n3 = __popcll(m3);
    const int N = n0 + n1 + n2 + n3;      // negatives in this row
    const int P = C_LOADED - N;           // positives
    const unsigned long long lm = (1ULL << lane) - 1ULL;

    float* ng = negl[wave];
    float* ps = posl[wave];
    const int nb1 = n0, nb2 = n0 + n1, nb3 = n0 + n1 + n2;
    const int pb1 = 64 - n0, pb2 = 128 - nb2, pb3 = 192 - nb3;
    if (l0 == 0) ng[__popcll(m0 & lm)] = r0 + NEG_PEN;
    else         ps[__popcll(~m0 & lm)] = r0;
    if (l1 == 0) ng[nb1 + __popcll(m1 & lm)] = r1 + NEG_PEN;
    else         ps[pb1 + __popcll(~m1 & lm)] = r1;
    if (l2 == 0) ng[nb2 + __popcll(m2 & lm)] = r2 + NEG_PEN;
    else         ps[pb2 + __popcll(~m2 & lm)] = r2;
    if (l3 == 0) ng[nb3 + __popcll(m3 & lm)] = r3 + NEG_PEN;
    else         ps[pb3 + __popcll(~m3 & lm)] = r3;

    const int Npad = (N + 7) & ~7;
    if (lane < Npad - N) ng[N + lane] = -1e30f;   // pad -> relu==0

    // wave-synchronous: all this wave's ds_writes complete before reads
    asm volatile("s_waitcnt lgkmcnt(0)" ::: "memory");

    float acc = 0.f;
    if (P > 0) {
        const int qmax = (P + 63) >> 6;   // wave-uniform
        float rp0 = 3e30f, rp1 = 3e30f, rp2 = 3e30f, rp3 = 3e30f;
        if (lane < P)       rp0 = ps[lane];
        if (lane + 64 < P)  rp1 = ps[lane + 64];
        if (lane + 128 < P) rp2 = ps[lane + 128];
        if (lane + 192 < P) rp3 = ps[lane + 192];
        const float4* n4 = (const float4*)ng;
        const int G = Npad >> 2;          // multiple of 2
        switch (qmax) {
        case 1:  acc = pair_loop<1>(n4, G, rp0, rp1, rp2, rp3); break;
        case 2:  acc = pair_loop<2>(n4, G, rp0, rp1, rp2, rp3); break;
        case 3:  acc = pair_loop<3>(n4, G, rp0, rp1, rp2, rp3); break;
        default: acc = pair_loop<4>(n4, G, rp0, rp1, rp2, rp3); break;
        }
    }

    // full-wave shuffle reduction
#pragma unroll
    for (int off = 32; off > 0; off >>= 1) {
        acc += __shfl_down(acc, off, 64);
    }

    int fin = 0;
    if (lane == 0) {
        PVU v;
        v.f = make_float2(acc, (P > 0) ? 1.0f : 0.0f);
        // publish via RMW (executes at coherence point)
        (void)__hip_atomic_exchange(&pv[row], v.u, __ATOMIC_RELAXED,
                                    __HIP_MEMORY_SCOPE_AGENT);
        // pv exchange completed at LLC before the line bump issues
        asm volatile("s_waitcnt vmcnt(0)" ::: "memory");
        unsigned int v1 = __hip_atomic_fetch_add(
            &lines[(row & (NLINES - 1)) * 16], 1u,
            __ATOMIC_RELAXED, __HIP_MEMORY_SCOPE_AGENT);
        if ((v1 & 31u) == 31u) {          // unique line-closer
            unsigned int v2 = __hip_atomic_fetch_add(
                lvl2, 1u, __ATOMIC_RELAXED, __HIP_MEMORY_SCOPE_AGENT);
            if ((v2 & 63u) == 63u) fin = 1;   // unique last row
        }
    }
    fin = __shfl(fin, 0, 64);

    if (fin) {                            // one wave reduces all 2048 partials
        float ss = 0.f, sv = 0.f;
#pragma unroll
        for (int k = 0; k < 32; ++k) {    // coalesced: lane-adjacent rows
            PVU v;
            v.u = __hip_atomic_load(&pv[k * 64 + lane], __ATOMIC_RELAXED,
                                    __HIP_MEMORY_SCOPE_AGENT);
            ss += v.f.x;
            sv += v.f.y;
        }
#pragma unroll
        for (int off = 32; off > 0; off >>= 1) {
            ss += __shfl_down(ss, off, 64);
            sv += __shfl_down(sv, off, 64);
        }
        if (lane == 0) out[0] = ss / sv;
    }
}

extern "C" void kernel_launch(void* const* d_in, const int* in_sizes, int n_in,
                              void* d_out, int out_size, void* d_ws, size_t ws_size,
                              hipStream_t stream) {
    const float* ranks  = (const float*)d_in[0];
    const int*   labels = (const int*)d_in[1];
    const int*   ids    = (const int*)d_in[2];
    float* out = (float*)d_out;

    unsigned long long* pv = (unsigned long long*)d_ws;
    unsigned int* lines = (unsigned int*)((char*)d_ws + 16384);
    unsigned int* lvl2  = (unsigned int*)((char*)d_ws + 20480);

    rank_loss_fused<<<GRID, 256, 0, stream>>>(ranks, labels, ids,
                                              pv, lines, lvl2, out);
}